// Round 1
// baseline (115.237 us; speedup 1.0000x reference)
//
#include <hip/hip_runtime.h>
#include <hip/hip_bf16.h>

// TTCN: h=relu(X@W1+b1); h=relu(h@W2+b2); filt=h@W3+b3; masked softmax over Lx;
// out[n,k]=relu(sum_{l,d} X[n,l,d]*softmax(filt)[n,l,k,d] + T_bias[k])
// N=128, LX=512, D=32, K=63, C=2016.
// R10: eliminate kern_prep (3 dispatches -> 2).
//  - mask scan moved in-kernel: wave-parallel 8-tokens/lane ballot-free prefix
//    scan (6 shfl_up rounds). Deterministic, identical ordering to old scan.
//  - W1/W2/b1 fragments packed per-block into LDS (L2-hot, ~6KB).
//  - W3fr packing done by 128 extra blocks at the FRONT of the mlp grid
//    (overlapped with MLP; kernel boundary orders it before kern_att).
//  - pad rows no longer zeroed in memory: kern_att masks the last chunk in
//    registers (A-rows and x lanes with row>=cnt -> 0), so pads contribute
//    exactly exp2(0)=1.0 to S (subtracted) and 0 to O, as before.
// Biases ride the MFMA K-dim: h1[63]=1 & W2 row63=b2 => H[:,63]=1;
// W3fr row63 = b3*log2e (whole W3 prescaled by log2e -> raw v_exp_f32).

#define N_   128
#define LX_  512
#define D_   32
#define K_   63
#define C_   2016
#define LOG2E 1.44269504088896f

typedef __bf16 bf16x8 __attribute__((ext_vector_type(8)));
typedef float floatx4 __attribute__((ext_vector_type(4)));
typedef float floatx2 __attribute__((ext_vector_type(2)));

static __device__ __forceinline__ floatx4 mfma16(bf16x8 a, bf16x8 b, floatx4 c) {
  return __builtin_amdgcn_mfma_f32_16x16x32_bf16(a, b, c, 0, 0, 0);
}

// ws layout (bytes)
#define HC_OFF   0u                        // 128n x 512row x 64 bf16 = 8 MiB (compacted)
#define XT_OFF   (8u * 1024u * 1024u)      // 128n x 32chunk x 32d x 16row f32 = 8 MiB
#define W3FR_OFF (16u * 1024u * 1024u)     // 129024 bf16 frag-packed, *log2e, row63=b3*log2e

// ---------------- M: blocks 0..127 pack W3fr; blocks 128..1151 do MLP -------
// MLP path: one 16-token tile per wave; barrier-free MFMA part (per-wave LDS
// transpose only); in-wave mask prefix scan replaces the old prep kernel.
__global__ __launch_bounds__(256) void kern_mlp(
    const float* __restrict__ X, const float* __restrict__ Mk,
    const float* __restrict__ W1, const float* __restrict__ b1,
    const float* __restrict__ W2, const float* __restrict__ b2,
    const float* __restrict__ W3, const float* __restrict__ b3,
    __bf16* __restrict__ W3fr, __bf16* __restrict__ Hc,
    float* __restrict__ Xt) {
  const int tid = threadIdx.x;

  if (blockIdx.x < 128) {   // ---- W3fr packer blocks (front of grid, overlap)
    for (int g = blockIdx.x * 256 + tid; g < 129024; g += 128 * 256) {
      // [tile21][i6][h2][l16][quad][8], *log2e, row63 = b3*log2e
      const int j = g & 7, quad = (g >> 3) & 3, l16v = (g >> 5) & 15, h = (g >> 9) & 1;
      const int rest = g >> 10, i = rest % 6, tile = rest / 6;
      const int cch = tile * 96 + i * 16 + l16v;
      const int t = h * 32 + quad * 8 + j;
      W3fr[g] = (__bf16)(((t < K_) ? W3[(size_t)t * C_ + cch] : b3[cch]) * LOG2E);
    }
    return;
  }

  __shared__ float h1s[4][16][68];                 // per-wave transpose tile
  __shared__ __align__(16) __bf16 W1s[2048];       // [i4][l16][quad][8]
  __shared__ __align__(16) __bf16 W2s[4096];       // [i4][h2][l16][quad][8]
  __shared__ float b1s[64];

  const int w = tid >> 6, lane = tid & 63, quad = lane >> 4, l16 = lane & 15;
  const int bid = blockIdx.x - 128;
  const int tok0 = bid * 64 + w * 16;
  const int n = tok0 >> 9;
  const int tile0 = tok0 & 511;

  // issue X + mask loads early (latency hidden under the LDS weight packing)
  const float* xp = X + (size_t)(tok0 + l16) * D_ + quad * 8;
  const float4 xa = *(const float4*)xp;
  const float4 xb = *(const float4*)(xp + 4);
  const float4 mq0 = *(const float4*)(Mk + n * 512 + lane * 8);
  const float4 mq1 = *(const float4*)(Mk + n * 512 + lane * 8 + 4);

  // ---- pack W1/W2/b1 fragments into LDS (every block; W1+W2 = 24KB, L2-hot)
  for (int g = tid; g < 2048; g += 256) {          // W1s: [i4][l16][quad][8]
    const int j = g & 7, qd = (g >> 3) & 3, lv = (g >> 5) & 15, i = g >> 9;
    const int ch = i * 16 + lv, t = qd * 8 + j;
    W1s[g] = (__bf16)((ch < K_) ? W1[t * K_ + ch] : 0.f);
  }
  for (int g = tid; g < 4096; g += 256) {          // W2s: row63=b2, [63][63]=1
    const int j = g & 7, qd = (g >> 3) & 3, lv = (g >> 5) & 15, h = (g >> 9) & 1;
    const int i = g >> 10;
    const int ch = i * 16 + lv, t = h * 32 + qd * 8 + j;
    float v;
    if (t < K_) v = (ch < K_) ? W2[t * K_ + ch] : 0.f;
    else        v = (ch < K_) ? b2[ch] : 1.f;
    W2s[g] = (__bf16)v;
  }
  if (tid < 64) b1s[tid] = (tid < K_) ? b1[tid] : 0.f;
  __syncthreads();

  // ---- wave-parallel mask prefix scan (8 tokens/lane, full n)
  unsigned mbits = (mq0.x > 0.5f ? 1u : 0u) | (mq0.y > 0.5f ? 2u : 0u) |
                   (mq0.z > 0.5f ? 4u : 0u) | (mq0.w > 0.5f ? 8u : 0u) |
                   (mq1.x > 0.5f ? 16u : 0u) | (mq1.y > 0.5f ? 32u : 0u) |
                   (mq1.z > 0.5f ? 64u : 0u) | (mq1.w > 0.5f ? 128u : 0u);
  const int pc = __popc(mbits);
  int scan = pc;
#pragma unroll
  for (int d = 1; d < 64; d <<= 1) {
    const int t = __shfl_up(scan, d);
    if (lane >= d) scan += t;
  }
  const int excl = scan - pc;   // masked tokens before this lane's 8 tokens

  // position of token tile0+l16 (X compaction) and of tokens quad*4+r (H rows)
  const int jA = (tile0 >> 3) + (l16 >> 3), bA = l16 & 7;
  const unsigned mA = (unsigned)__shfl((int)mbits, jA);
  const int eA = __shfl(excl, jA);
  const int px = ((mA >> bA) & 1u) ? (eA + __popc(mA & ((1u << bA) - 1u))) : -1;
  int pr[4];
#pragma unroll
  for (int r = 0; r < 4; ++r) {
    const int lr = quad * 4 + r;
    const int jR = (tile0 >> 3) + (lr >> 3), bR = lr & 7;
    const unsigned mR = (unsigned)__shfl((int)mbits, jR);
    const int eR = __shfl(excl, jR);
    pr[r] = ((mR >> bR) & 1u) ? (eR + __popc(mR & ((1u << bR) - 1u))) : -1;
  }

  bf16x8 b1f[4], b2f[4][2];
  float b1v[4];
#pragma unroll
  for (int i = 0; i < 4; ++i) {
    b1f[i]    = *(const bf16x8*)(&W1s[((i * 16 + l16) * 4 + quad) * 8]);
    b2f[i][0] = *(const bf16x8*)(&W2s[(((i * 2 + 0) * 16 + l16) * 4 + quad) * 8]);
    b2f[i][1] = *(const bf16x8*)(&W2s[(((i * 2 + 1) * 16 + l16) * 4 + quad) * 8]);
    b1v[i] = b1s[i * 16 + l16];
  }

  bf16x8 a1;
  a1[0]=(__bf16)xa.x; a1[1]=(__bf16)xa.y; a1[2]=(__bf16)xa.z; a1[3]=(__bf16)xa.w;
  a1[4]=(__bf16)xb.x; a1[5]=(__bf16)xb.y; a1[6]=(__bf16)xb.z; a1[7]=(__bf16)xb.w;

  if (px >= 0) {  // compacted X f32 d-planes (mask==1 here, so X*mask == X)
    float* xtp = Xt + ((size_t)(n * 32 + (px >> 4)) * 32 + quad * 8) * 16 + (px & 15);
    const float vals[8] = {xa.x, xa.y, xa.z, xa.w, xb.x, xb.y, xb.z, xb.w};
#pragma unroll
    for (int j = 0; j < 8; ++j) xtp[j * 16] = vals[j];
  }

#pragma unroll
  for (int i = 0; i < 4; ++i) {
    floatx4 acc = {0.f, 0.f, 0.f, 0.f};
    acc = mfma16(a1, b1f[i], acc);
#pragma unroll
    for (int r = 0; r < 4; ++r) {
      float v = fmaxf(acc[r] + b1v[i], 0.f);
      if (i == 3 && l16 == 15) v = 1.f;   // h1 col63 := 1 (layer-2 bias row)
      h1s[w][quad * 4 + r][i * 16 + l16] = v;
    }
  }
  // no barrier: h1s[w] is produced and consumed by the same wave (lgkmcnt orders)

  const float* hrow = &h1s[w][l16][0];
  const float4 p0 = *(const float4*)(hrow + quad * 8);
  const float4 p1 = *(const float4*)(hrow + quad * 8 + 4);
  const float4 p2 = *(const float4*)(hrow + 32 + quad * 8);
  const float4 p3 = *(const float4*)(hrow + 32 + quad * 8 + 4);
  bf16x8 a20, a21;
  a20[0]=(__bf16)p0.x; a20[1]=(__bf16)p0.y; a20[2]=(__bf16)p0.z; a20[3]=(__bf16)p0.w;
  a20[4]=(__bf16)p1.x; a20[5]=(__bf16)p1.y; a20[6]=(__bf16)p1.z; a20[7]=(__bf16)p1.w;
  a21[0]=(__bf16)p2.x; a21[1]=(__bf16)p2.y; a21[2]=(__bf16)p2.z; a21[3]=(__bf16)p2.w;
  a21[4]=(__bf16)p3.x; a21[5]=(__bf16)p3.y; a21[6]=(__bf16)p3.z; a21[7]=(__bf16)p3.w;

#pragma unroll
  for (int i = 0; i < 4; ++i) {
    floatx4 acc = {0.f, 0.f, 0.f, 0.f};
    acc = mfma16(a20, b2f[i][0], acc);
    acc = mfma16(a21, b2f[i][1], acc);  // bias via k=63 (h1 col63 == 1)
#pragma unroll
    for (int r = 0; r < 4; ++r) {
      if (pr[r] >= 0)
        Hc[((size_t)(n * 512 + pr[r])) * 64 + i * 16 + l16] =
            (__bf16)fmaxf(acc[r], 0.f);
    }
  }
}

// ---------------- A: fused logits-MFMA + exp2 + pooling (compacted rows) -----
// Block = (n, 96-ch tile). 16-row chunks round-robin over waves (c = w; c += 4),
// software-pipelined 1 chunk deep. s accumulated unconditionally (pk_add pairs);
// pad rows are register-masked in the LAST chunk (A rows and x -> 0), so each
// contributes exactly exp2(0)=1.0 to s, subtracted as a scalar at the end.
__global__ __launch_bounds__(256) void kern_att(
    const __bf16* __restrict__ Hc, const float* __restrict__ Xt,
    const __bf16* __restrict__ W3fr, const float* __restrict__ Mk,
    const float* __restrict__ Tb, float* __restrict__ out) {
  __shared__ float redS[4][96], redO[4][96];
  __shared__ float rbuf[96];

  const int bid = blockIdx.x;
  const int idx = bid >> 3;
  const int n = (bid & 7) * 16 + idx / 21;
  const int bt = idx % 21;
  const int tid = threadIdx.x;
  const int w = tid >> 6, lane = tid & 63, quad = lane >> 4, l16 = lane & 15;

  // cnt[n] recomputed locally: 8 mask values/lane + 6-round xor reduce
  const float4 mq0 = *(const float4*)(Mk + n * 512 + lane * 8);
  const float4 mq1 = *(const float4*)(Mk + n * 512 + lane * 8 + 4);

  bf16x8 bf[6][2];
#pragma unroll
  for (int i = 0; i < 6; ++i) {
    bf[i][0] = *(const bf16x8*)(W3fr + ((((bt * 6 + i) * 2 + 0) * 16 + l16) * 4 + quad) * 8);
    bf[i][1] = *(const bf16x8*)(W3fr + ((((bt * 6 + i) * 2 + 1) * 16 + l16) * 4 + quad) * 8);
  }

  int pc = (mq0.x > 0.5f) + (mq0.y > 0.5f) + (mq0.z > 0.5f) + (mq0.w > 0.5f) +
           (mq1.x > 0.5f) + (mq1.y > 0.5f) + (mq1.z > 0.5f) + (mq1.w > 0.5f);
#pragma unroll
  for (int d = 1; d < 64; d <<= 1) pc += __shfl_xor(pc, d);
  const int cntn = pc;

  const int nch = (cntn + 15) >> 4;                 // 16-row chunks (~14..19)
  // lane base pointers; chunk c adds c*1024 (H, bf16) / c*512 (Xt, f32)
  const __bf16* Hb = Hc + ((size_t)n << 9) * 64 + (size_t)l16 * 64 + quad * 8;
  const float*  Xb = Xt + ((size_t)n * 32) * 512 + l16 * 16 + quad * 4;

  floatx2 s2[3] = {{0.f, 0.f}, {0.f, 0.f}, {0.f, 0.f}};
  float o[6] = {0, 0, 0, 0, 0, 0};

  bf16x8 zb;
#pragma unroll
  for (int j = 0; j < 8; ++j) zb[j] = (__bf16)0.f;

  int c = w;                                        // nch >= 13 > 4, always valid
  bf16x8 a0 = *(const bf16x8*)(Hb + (size_t)c * 1024);
  bf16x8 a1 = *(const bf16x8*)(Hb + (size_t)c * 1024 + 32);
  floatx4 xl4 = *(const floatx4*)(Xb + c * 512);
  floatx4 xh4 = *(const floatx4*)(Xb + c * 512 + 256);

#pragma unroll 1
  while (c < nch) {
    const int cn = c + 4;
    bf16x8 na0, na1;
    floatx4 nxl, nxh;
    if (cn < nch) {                                 // wave-uniform prefetch
      na0 = *(const bf16x8*)(Hb + (size_t)cn * 1024);
      na1 = *(const bf16x8*)(Hb + (size_t)cn * 1024 + 32);
      nxl = *(const floatx4*)(Xb + cn * 512);
      nxh = *(const floatx4*)(Xb + cn * 512 + 256);
    }

    if (c == nch - 1) {                             // register-mask pad rows
      const int rem = cntn - (c << 4);              // valid rows: 1..16
      if (l16 >= rem) { a0 = zb; a1 = zb; }         // A row l16 -> logit == 0
#pragma unroll
      for (int r = 0; r < 4; ++r)
        if (quad * 4 + r >= rem) { xl4[r] = 0.f; xh4[r] = 0.f; }
    }

#pragma unroll
    for (int t = 0; t < 3; ++t) {
      floatx4 accE = {0.f, 0.f, 0.f, 0.f};
      floatx4 accO = {0.f, 0.f, 0.f, 0.f};
      accE = mfma16(a0, bf[2 * t][0], accE);
      accE = mfma16(a1, bf[2 * t][1], accE);        // logit*log2e incl. b3
      accO = mfma16(a0, bf[2 * t + 1][0], accO);
      accO = mfma16(a1, bf[2 * t + 1][1], accO);
#pragma unroll
      for (int r = 0; r < 4; ++r) {
        floatx2 e2;
        e2.x = __builtin_amdgcn_exp2f(accE[r]);
        e2.y = __builtin_amdgcn_exp2f(accO[r]);
        s2[t] += e2;                                // pad rows add exactly 1.0
        o[2 * t]     = fmaf(e2.x, xl4[r], o[2 * t]);     // x==0 on pad rows
        o[2 * t + 1] = fmaf(e2.y, xh4[r], o[2 * t + 1]);
      }
    }

    c = cn;
    a0 = na0; a1 = na1; xl4 = nxl; xh4 = nxh;       // garbage on exit iter: unused
  }

  // reduce the 4 quads (row groups) within each wave
#pragma unroll
  for (int t = 0; t < 3; ++t) {
    s2[t].x += __shfl_xor(s2[t].x, 16); s2[t].x += __shfl_xor(s2[t].x, 32);
    s2[t].y += __shfl_xor(s2[t].y, 16); s2[t].y += __shfl_xor(s2[t].y, 32);
  }
#pragma unroll
  for (int i = 0; i < 6; ++i) {
    o[i] += __shfl_xor(o[i], 16);
    o[i] += __shfl_xor(o[i], 32);
  }
  if (quad == 0) {
#pragma unroll
    for (int t = 0; t < 3; ++t) {
      redS[w][(2 * t) * 16 + l16]     = s2[t].x;
      redS[w][(2 * t + 1) * 16 + l16] = s2[t].y;
    }
#pragma unroll
    for (int i = 0; i < 6; ++i) redO[w][i * 16 + l16] = o[i];
  }
  __syncthreads();
  if (tid < 96) {
    const float pad = (float)(nch * 16 - cntn);     // exact pad contribution to S
    const float S = redS[0][tid] + redS[1][tid] + redS[2][tid] + redS[3][tid] - pad;
    const float O = redO[0][tid] + redO[1][tid] + redO[2][tid] + redO[3][tid];
    rbuf[tid] = O / S;
  }
  __syncthreads();
  if (tid < 3) {
    float acc = 0.f;
#pragma unroll
    for (int dd = 0; dd < 32; ++dd) acc += rbuf[tid * 32 + dd];
    const int k = bt * 3 + tid;
    out[n * K_ + k] = fmaxf(acc + Tb[k], 0.f);
  }
}

extern "C" void kernel_launch(void* const* d_in, const int* in_sizes, int n_in,
                              void* d_out, int out_size, void* d_ws, size_t ws_size,
                              hipStream_t stream) {
  const float* X  = (const float*)d_in[0];
  const float* Mk = (const float*)d_in[1];
  const float* W1 = (const float*)d_in[2];
  const float* b1 = (const float*)d_in[3];
  const float* W2 = (const float*)d_in[4];
  const float* b2 = (const float*)d_in[5];
  const float* W3 = (const float*)d_in[6];
  const float* b3 = (const float*)d_in[7];
  const float* Tb = (const float*)d_in[8];
  float* out = (float*)d_out;

  char* ws = (char*)d_ws;
  __bf16* Hc   = (__bf16*)(ws + HC_OFF);
  float*  Xt   = (float*)(ws + XT_OFF);
  __bf16* W3fr = (__bf16*)(ws + W3FR_OFF);

  kern_mlp<<<128 + N_ * LX_ / 64, 256, 0, stream>>>(X, Mk, W1, b1, W2, b2, W3, b3,
                                                    W3fr, Hc, Xt);
  kern_att<<<N_ * 21, 256, 0, stream>>>(Hc, Xt, W3fr, Mk, Tb, out);
}

// Round 2
// 112.715 us; speedup vs baseline: 1.0224x; 1.0224x over previous
//
#include <hip/hip_runtime.h>
#include <hip/hip_bf16.h>

// TTCN: h=relu(X@W1+b1); h=relu(h@W2+b2); filt=h@W3+b3; masked softmax over Lx;
// out[n,k]=relu(sum_{l,d} X[n,l,d]*softmax(filt)[n,l,k,d] + T_bias[k])
// N=128, LX=512, D=32, K=63, C=2016.
// R11 = revert to R5/R0 (measured optimum, 112.05 us). R10's prep-fusion was
// neutral-to-negative (115.2): launch-boundary cost is ~0 within noise; the
// packer blocks competed with MLP blocks on kern_att's critical path.
// Mask compaction (masked rows contribute exactly 0) + pad-count trick:
// pad rows have H==0 -> logit==0 -> e==exp2(0)==1.0 exactly, so s accumulates
// unconditionally (v_pk_add_f32 pairs) and the scalar pad count is subtracted
// at the end. X is pre-transposed to f32 d-planes so the epilogue x-loads are
// 2 coalesced b128/wave. 16-row chunks round-robin over waves (tail waste ~5%).
// Biases ride the MFMA K-dim: h1[63]=1 & W2 row63=b2 => H[:,63]=1;
// W3fr row63 = b3*log2e (whole W3 prescaled by log2e -> raw v_exp_f32).

#define N_   128
#define LX_  512
#define D_   32
#define K_   63
#define C_   2016
#define LOG2E 1.44269504088896f

typedef __bf16 bf16x8 __attribute__((ext_vector_type(8)));
typedef float floatx4 __attribute__((ext_vector_type(4)));
typedef float floatx2 __attribute__((ext_vector_type(2)));

static __device__ __forceinline__ floatx4 mfma16(bf16x8 a, bf16x8 b, floatx4 c) {
  return __builtin_amdgcn_mfma_f32_16x16x32_bf16(a, b, c, 0, 0, 0);
}

// ws layout (bytes)
#define HC_OFF   0u                        // 128n x 512row x 64 bf16 = 8 MiB (compacted)
#define XT_OFF   (8u * 1024u * 1024u)      // 128n x 32chunk x 32d x 16row f32 = 8 MiB
#define W3FR_OFF (16u * 1024u * 1024u)     // 129024 bf16 frag-packed, *log2e, row63=b3*log2e
#define W1FR_OFF (W3FR_OFF + 258048u)      // 2048 bf16
#define W2FR_OFF (W1FR_OFF + 4096u)        // 4096 bf16
#define B1_OFF   (W2FR_OFF + 8192u)        // 64 f32
#define POS_OFF  (B1_OFF + 256u)           // 65536 i32
#define CNT_OFF  (POS_OFF + 262144u)       // 128 i32

// ---------------- P: mask scan + pad-zeroing + weight frag packing -----------
__global__ __launch_bounds__(256) void kern_prep(
    const float* __restrict__ Mk,
    const float* __restrict__ W1, const float* __restrict__ b1,
    const float* __restrict__ W2, const float* __restrict__ b2,
    const float* __restrict__ W3, const float* __restrict__ b3,
    __bf16* __restrict__ W3fr, __bf16* __restrict__ W1fr,
    __bf16* __restrict__ W2fr, float* __restrict__ b1pad,
    int* __restrict__ pos, int* __restrict__ cnt,
    __bf16* __restrict__ Hc, float* __restrict__ Xt) {
  const int n = blockIdx.x, tid = threadIdx.x;
  __shared__ int s_cnt;

  if (tid < 64) {                       // wave 0: exclusive scan of the mask
    const int lane = tid;
    int running = 0;
#pragma unroll
    for (int c = 0; c < 8; ++c) {
      const int l = c * 64 + lane;
      const float mkv = Mk[n * LX_ + l];
      const unsigned long long b = __ballot(mkv > 0.5f);
      const int mypos = running + __popcll(b & ((1ull << lane) - 1ull));
      pos[n * LX_ + l] = (mkv > 0.5f) ? mypos : -1;
      running += __popcll(b);
    }
    if (lane == 0) { cnt[n] = running; s_cnt = running; }
  }
  __syncthreads();

  // zero padding rows [cnt, ceil64(cnt)): Hc (8 float4/row) + Xt (32 dword/row)
  const int c0 = s_cnt, c1 = (c0 + 63) & ~63;
  const float4 z = {0.f, 0.f, 0.f, 0.f};
  for (int idx = tid; idx < (c1 - c0) * 40; idx += 256) {
    const int row = c0 + idx / 40, q = idx % 40;
    if (q < 8) {
      *(float4*)(Hc + ((size_t)(n * 512 + row)) * 64 + q * 8) = z;
    } else {
      const int d = q - 8;
      Xt[((size_t)(n * 32 + (row >> 4)) * 32 + d) * 16 + (row & 15)] = 0.f;
    }
  }

  // weight packing (grid-stride over all slots)
  for (int g = n * 256 + tid; g < 129024 + 2048 + 4096 + 64; g += N_ * 256) {
    if (g < 129024) {                     // W3fr: [tile21][i6][h2][l16][quad][8], *log2e
      const int j = g & 7, quad = (g >> 3) & 3, l16 = (g >> 5) & 15, h = (g >> 9) & 1;
      const int rest = g >> 10, i = rest % 6, tile = rest / 6;
      const int c = tile * 96 + i * 16 + l16;
      const int t = h * 32 + quad * 8 + j;
      W3fr[g] = (__bf16)(((t < K_) ? W3[(size_t)t * C_ + c] : b3[c]) * LOG2E);
    } else if (g < 129024 + 2048) {       // W1fr: [i4][l16][quad][8]
      const int g2 = g - 129024;
      const int j = g2 & 7, quad = (g2 >> 3) & 3, l16 = (g2 >> 5) & 15, i = g2 >> 9;
      const int ch = i * 16 + l16, t = quad * 8 + j;
      W1fr[g2] = (__bf16)((ch < K_) ? W1[t * K_ + ch] : 0.f);
    } else if (g < 129024 + 2048 + 4096) {// W2fr: [i4][h2][l16][quad][8], row63=b2, [63][63]=1
      const int g2 = g - 129024 - 2048;
      const int j = g2 & 7, quad = (g2 >> 3) & 3, l16 = (g2 >> 5) & 15, h = (g2 >> 9) & 1;
      const int i = g2 >> 10;
      const int ch = i * 16 + l16, t = h * 32 + quad * 8 + j;
      float v;
      if (t < K_) v = (ch < K_) ? W2[t * K_ + ch] : 0.f;
      else        v = (ch < K_) ? b2[ch] : 1.f;
      W2fr[g2] = (__bf16)v;
    } else {
      const int g2 = g - 129024 - 2048 - 4096;
      b1pad[g2] = (g2 < K_) ? b1[g2] : 0.f;
    }
  }
}

// ---------------- M: Hc(bf16, compacted) = MLP(X); Xt = compacted X planes ---
// One 16-token tile per wave; barrier-free (per-wave LDS transpose only).
__global__ __launch_bounds__(256) void kern_mlp(
    const float* __restrict__ X, const __bf16* __restrict__ W1fr,
    const __bf16* __restrict__ W2fr, const float* __restrict__ b1pad,
    const int* __restrict__ pos, __bf16* __restrict__ Hc,
    float* __restrict__ Xt) {
  __shared__ float h1s[4][16][68];   // per-wave transpose tile
  const int tid = threadIdx.x;
  const int w = tid >> 6, lane = tid & 63, quad = lane >> 4, l16 = lane & 15;

  bf16x8 b1f[4], b2f[4][2];
  float b1v[4];
#pragma unroll
  for (int i = 0; i < 4; ++i) {
    b1f[i]    = *(const bf16x8*)(W1fr + ((i * 16 + l16) * 4 + quad) * 8);
    b2f[i][0] = *(const bf16x8*)(W2fr + (((i * 2 + 0) * 16 + l16) * 4 + quad) * 8);
    b2f[i][1] = *(const bf16x8*)(W2fr + (((i * 2 + 1) * 16 + l16) * 4 + quad) * 8);
    b1v[i] = b1pad[i * 16 + l16];
  }

  const int tok0 = blockIdx.x * 64 + w * 16;
  const int n = tok0 >> 9;
  const float* xp = X + (size_t)(tok0 + l16) * D_ + quad * 8;
  const float4 xa = *(const float4*)xp;
  const float4 xb = *(const float4*)(xp + 4);
  bf16x8 a1;
  a1[0]=(__bf16)xa.x; a1[1]=(__bf16)xa.y; a1[2]=(__bf16)xa.z; a1[3]=(__bf16)xa.w;
  a1[4]=(__bf16)xb.x; a1[5]=(__bf16)xb.y; a1[6]=(__bf16)xb.z; a1[7]=(__bf16)xb.w;

  // compaction indirection
  const int px = pos[tok0 + l16];
  int pr[4];
#pragma unroll
  for (int r = 0; r < 4; ++r) pr[r] = pos[tok0 + quad * 4 + r];

  if (px >= 0) {  // compacted X f32 d-planes (mask==1 here, so X*mask == X)
    float* xtp = Xt + ((size_t)(n * 32 + (px >> 4)) * 32 + quad * 8) * 16 + (px & 15);
    const float vals[8] = {xa.x, xa.y, xa.z, xa.w, xb.x, xb.y, xb.z, xb.w};
#pragma unroll
    for (int j = 0; j < 8; ++j) xtp[j * 16] = vals[j];
  }

#pragma unroll
  for (int i = 0; i < 4; ++i) {
    floatx4 acc = {0.f, 0.f, 0.f, 0.f};
    acc = mfma16(a1, b1f[i], acc);
#pragma unroll
    for (int r = 0; r < 4; ++r) {
      float v = fmaxf(acc[r] + b1v[i], 0.f);
      if (i == 3 && l16 == 15) v = 1.f;   // h1 col63 := 1 (layer-2 bias row)
      h1s[w][quad * 4 + r][i * 16 + l16] = v;
    }
  }
  // no barrier: h1s[w] is produced and consumed by the same wave (lgkmcnt orders)

  const float* hrow = &h1s[w][l16][0];
  const float4 p0 = *(const float4*)(hrow + quad * 8);
  const float4 p1 = *(const float4*)(hrow + quad * 8 + 4);
  const float4 p2 = *(const float4*)(hrow + 32 + quad * 8);
  const float4 p3 = *(const float4*)(hrow + 32 + quad * 8 + 4);
  bf16x8 a20, a21;
  a20[0]=(__bf16)p0.x; a20[1]=(__bf16)p0.y; a20[2]=(__bf16)p0.z; a20[3]=(__bf16)p0.w;
  a20[4]=(__bf16)p1.x; a20[5]=(__bf16)p1.y; a20[6]=(__bf16)p1.z; a20[7]=(__bf16)p1.w;
  a21[0]=(__bf16)p2.x; a21[1]=(__bf16)p2.y; a21[2]=(__bf16)p2.z; a21[3]=(__bf16)p2.w;
  a21[4]=(__bf16)p3.x; a21[5]=(__bf16)p3.y; a21[6]=(__bf16)p3.z; a21[7]=(__bf16)p3.w;

#pragma unroll
  for (int i = 0; i < 4; ++i) {
    floatx4 acc = {0.f, 0.f, 0.f, 0.f};
    acc = mfma16(a20, b2f[i][0], acc);
    acc = mfma16(a21, b2f[i][1], acc);  // bias via k=63 (h1 col63 == 1)
#pragma unroll
    for (int r = 0; r < 4; ++r) {
      if (pr[r] >= 0)
        Hc[((size_t)(n * 512 + pr[r])) * 64 + i * 16 + l16] =
            (__bf16)fmaxf(acc[r], 0.f);
    }
  }
}

// ---------------- A: fused logits-MFMA + exp2 + pooling (compacted rows) -----
// Block = (n, 96-ch tile). 16-row chunks round-robin over waves (c = w; c += 4),
// software-pipelined 1 chunk deep. s accumulated unconditionally (pk_add pairs);
// pad rows contribute exactly 1.0 each, subtracted as a scalar at the end.
__global__ __launch_bounds__(256) void kern_att(
    const __bf16* __restrict__ Hc, const float* __restrict__ Xt,
    const __bf16* __restrict__ W3fr, const int* __restrict__ cnt,
    const float* __restrict__ Tb, float* __restrict__ out) {
  __shared__ float redS[4][96], redO[4][96];
  __shared__ float rbuf[96];

  const int bid = blockIdx.x;
  const int idx = bid >> 3;
  const int n = (bid & 7) * 16 + idx / 21;
  const int bt = idx % 21;
  const int tid = threadIdx.x;
  const int w = tid >> 6, lane = tid & 63, quad = lane >> 4, l16 = lane & 15;

  bf16x8 bf[6][2];
#pragma unroll
  for (int i = 0; i < 6; ++i) {
    bf[i][0] = *(const bf16x8*)(W3fr + ((((bt * 6 + i) * 2 + 0) * 16 + l16) * 4 + quad) * 8);
    bf[i][1] = *(const bf16x8*)(W3fr + ((((bt * 6 + i) * 2 + 1) * 16 + l16) * 4 + quad) * 8);
  }

  const int cntn = cnt[n];
  const int nch = (cntn + 15) >> 4;                 // 16-row chunks (~14..19)
  // lane base pointers; chunk c adds c*1024 (H, bf16) / c*512 (Xt, f32)
  const __bf16* Hb = Hc + ((size_t)n << 9) * 64 + (size_t)l16 * 64 + quad * 8;
  const float*  Xb = Xt + ((size_t)n * 32) * 512 + l16 * 16 + quad * 4;

  floatx2 s2[3] = {{0.f, 0.f}, {0.f, 0.f}, {0.f, 0.f}};
  float o[6] = {0, 0, 0, 0, 0, 0};

  int c = w;                                        // nch >= 13 > 4, always valid
  bf16x8 a0 = *(const bf16x8*)(Hb + (size_t)c * 1024);
  bf16x8 a1 = *(const bf16x8*)(Hb + (size_t)c * 1024 + 32);
  float4 xl4 = *(const float4*)(Xb + c * 512);
  float4 xh4 = *(const float4*)(Xb + c * 512 + 256);

#pragma unroll 1
  while (c < nch) {
    const int cn = c + 4;
    bf16x8 na0, na1;
    float4 nxl, nxh;
    if (cn < nch) {                                 // wave-uniform prefetch
      na0 = *(const bf16x8*)(Hb + (size_t)cn * 1024);
      na1 = *(const bf16x8*)(Hb + (size_t)cn * 1024 + 32);
      nxl = *(const float4*)(Xb + cn * 512);
      nxh = *(const float4*)(Xb + cn * 512 + 256);
    }

#pragma unroll
    for (int t = 0; t < 3; ++t) {
      floatx4 accE = {0.f, 0.f, 0.f, 0.f};
      floatx4 accO = {0.f, 0.f, 0.f, 0.f};
      accE = mfma16(a0, bf[2 * t][0], accE);
      accE = mfma16(a1, bf[2 * t][1], accE);        // logit*log2e incl. b3
      accO = mfma16(a0, bf[2 * t + 1][0], accO);
      accO = mfma16(a1, bf[2 * t + 1][1], accO);
#pragma unroll
      for (int r = 0; r < 4; ++r) {
        floatx2 e2;
        e2.x = __builtin_amdgcn_exp2f(accE[r]);
        e2.y = __builtin_amdgcn_exp2f(accO[r]);
        s2[t] += e2;                                // pad rows add exactly 1.0
        o[2 * t]     = fmaf(e2.x, xl4[r], o[2 * t]);     // x==0 on pad rows
        o[2 * t + 1] = fmaf(e2.y, xh4[r], o[2 * t + 1]);
      }
    }

    c = cn;
    a0 = na0; a1 = na1; xl4 = nxl; xh4 = nxh;       // garbage on exit iter: unused
  }

  // reduce the 4 quads (row groups) within each wave
#pragma unroll
  for (int t = 0; t < 3; ++t) {
    s2[t].x += __shfl_xor(s2[t].x, 16); s2[t].x += __shfl_xor(s2[t].x, 32);
    s2[t].y += __shfl_xor(s2[t].y, 16); s2[t].y += __shfl_xor(s2[t].y, 32);
  }
#pragma unroll
  for (int i = 0; i < 6; ++i) {
    o[i] += __shfl_xor(o[i], 16);
    o[i] += __shfl_xor(o[i], 32);
  }
  if (quad == 0) {
#pragma unroll
    for (int t = 0; t < 3; ++t) {
      redS[w][(2 * t) * 16 + l16]     = s2[t].x;
      redS[w][(2 * t + 1) * 16 + l16] = s2[t].y;
    }
#pragma unroll
    for (int i = 0; i < 6; ++i) redO[w][i * 16 + l16] = o[i];
  }
  __syncthreads();
  if (tid < 96) {
    const float pad = (float)(nch * 16 - cntn);     // exact pad contribution to S
    const float S = redS[0][tid] + redS[1][tid] + redS[2][tid] + redS[3][tid] - pad;
    const float O = redO[0][tid] + redO[1][tid] + redO[2][tid] + redO[3][tid];
    rbuf[tid] = O / S;
  }
  __syncthreads();
  if (tid < 3) {
    float acc = 0.f;
#pragma unroll
    for (int dd = 0; dd < 32; ++dd) acc += rbuf[tid * 32 + dd];
    const int k = bt * 3 + tid;
    out[n * K_ + k] = fmaxf(acc + Tb[k], 0.f);
  }
}

extern "C" void kernel_launch(void* const* d_in, const int* in_sizes, int n_in,
                              void* d_out, int out_size, void* d_ws, size_t ws_size,
                              hipStream_t stream) {
  const float* X  = (const float*)d_in[0];
  const float* Mk = (const float*)d_in[1];
  const float* W1 = (const float*)d_in[2];
  const float* b1 = (const float*)d_in[3];
  const float* W2 = (const float*)d_in[4];
  const float* b2 = (const float*)d_in[5];
  const float* W3 = (const float*)d_in[6];
  const float* b3 = (const float*)d_in[7];
  const float* Tb = (const float*)d_in[8];
  float* out = (float*)d_out;

  char* ws = (char*)d_ws;
  __bf16* Hc    = (__bf16*)(ws + HC_OFF);
  float*  Xt    = (float*)(ws + XT_OFF);
  __bf16* W3fr  = (__bf16*)(ws + W3FR_OFF);
  __bf16* W1fr  = (__bf16*)(ws + W1FR_OFF);
  __bf16* W2fr  = (__bf16*)(ws + W2FR_OFF);
  float*  b1pad = (float*)(ws + B1_OFF);
  int*    pos   = (int*)(ws + POS_OFF);
  int*    cnt   = (int*)(ws + CNT_OFF);

  kern_prep<<<N_, 256, 0, stream>>>(Mk, W1, b1, W2, b2, W3, b3,
                                    W3fr, W1fr, W2fr, b1pad, pos, cnt, Hc, Xt);
  kern_mlp<<<N_ * LX_ / 64, 256, 0, stream>>>(X, W1fr, W2fr, b1pad, pos, Hc, Xt);
  kern_att<<<N_ * 21, 256, 0, stream>>>(Hc, Xt, W3fr, cnt, Tb, out);
}